// Round 10
// baseline (237.308 us; speedup 1.0000x reference)
//
#include <hip/hip_runtime.h>
#include <stdint.h>

// Shapes (fixed): x [4,2048,1024] f32, qkv_w [3072,1024] f32, out_w [1024,1024] f32,
// out_b [1024] f32, out [4,2048,1024] f32.
// Pipeline: cvt->bf16 (fused), gemm_bt qkv (128^2, proven ~860 TF; round-9's 256^2
// 2-barrier variant was 563 TF = the m112 result, reverted), flash attn v2 (64 q/wave:
// K/V LDS reads shared across both 32-q groups -> half the LDS traffic and half the
// barriers per unit work), gemm_bt out.

typedef __bf16 bfx8 __attribute__((ext_vector_type(8)));
typedef float f32x4 __attribute__((ext_vector_type(4)));
typedef float f32x16 __attribute__((ext_vector_type(16)));

__device__ __forceinline__ uint16_t f2b(float f) {
  uint32_t u = __float_as_uint(f);
  u += 0x7fff + ((u >> 16) & 1);   // RNE
  return (uint16_t)(u >> 16);
}

__device__ __forceinline__ uint32_t cvt_pk(float lo, float hi) {
  uint32_t r;
  asm("v_cvt_pk_bf16_f32 %0, %1, %2" : "=v"(r) : "v"(lo), "v"(hi));
  return r;
}

__device__ __forceinline__ void gld16(const void* g, void* l) {
  __builtin_amdgcn_global_load_lds((const __attribute__((address_space(1))) void*)g,
                                   (__attribute__((address_space(3))) void*)l,
                                   16, 0, 0);
}

// ---------------- fused f32 -> bf16 convert (8 elems/thread, 3 tensors) -----------
__global__ __launch_bounds__(256) void cvt_all(const float* __restrict__ x,
                                               const float* __restrict__ w1,
                                               const float* __restrict__ w2,
                                               uint16_t* __restrict__ xb,
                                               uint16_t* __restrict__ w1b,
                                               uint16_t* __restrict__ w2b) {
  int i = blockIdx.x * 256 + threadIdx.x;
  const float* in;
  uint16_t* out;
  if (i < 1048576) { in = x; out = xb; }
  else if (i < 1048576 + 393216) { in = w1; out = w1b; i -= 1048576; }
  else { in = w2; out = w2b; i -= 1048576 + 393216; }
  float4 a = ((const float4*)in)[2 * i];
  float4 b = ((const float4*)in)[2 * i + 1];
  union { uint16_t u[8]; uint4 v; } pk;
  pk.u[0] = f2b(a.x); pk.u[1] = f2b(a.y); pk.u[2] = f2b(a.z); pk.u[3] = f2b(a.w);
  pk.u[4] = f2b(b.x); pk.u[5] = f2b(b.y); pk.u[6] = f2b(b.z); pk.u[7] = f2b(b.w);
  ((uint4*)out)[i] = pk.v;
}

// ---------------- GEMM 128^2: C = A*B^T (+bias) ----------------
template <int OUTF32>
__global__ __launch_bounds__(256) void gemm_bt(const uint16_t* __restrict__ A,
                                               const uint16_t* __restrict__ B,
                                               void* __restrict__ Cout,
                                               const float* __restrict__ bias,
                                               int M, int N, int K, int nbx, int nwg) {
  __shared__ alignas(16) uint16_t As[2][128 * 32];
  __shared__ alignas(16) uint16_t Bs[2][128 * 32];

  int did = blockIdx.x;
  int wg = (did & 7) * (nwg >> 3) + (did >> 3);
  int bx = wg % nbx, by = wg / nbx;
  int m0 = by * 128, n0 = bx * 128;

  int tid = threadIdx.x;
  int lane = tid & 63, wid = tid >> 6;
  int wm = wid >> 1, wn = wid & 1;

  int rs = wid * 16 + (lane >> 2);
  int cs = (lane & 3) * 8;

  f32x4 acc[4][4] = {};

  auto stage = [&](int buf, int kt) {
    int k0 = kt * 32;
    gld16(&A[(size_t)(m0 + rs) * K + k0 + cs],      &As[buf][wid * 512]);
    gld16(&A[(size_t)(m0 + rs + 64) * K + k0 + cs], &As[buf][wid * 512 + 2048]);
    gld16(&B[(size_t)(n0 + rs) * K + k0 + cs],      &Bs[buf][wid * 512]);
    gld16(&B[(size_t)(n0 + rs + 64) * K + k0 + cs], &Bs[buf][wid * 512 + 2048]);
  };

  stage(0, 0);
  __syncthreads();

  int nk = K >> 5;
  int cur = 0;
  int ko = (lane >> 4) * 8;
  for (int kt = 0; kt < nk; ++kt) {
    if (kt + 1 < nk) stage(cur ^ 1, kt + 1);
    bfx8 a[4], b[4];
#pragma unroll
    for (int mi = 0; mi < 4; ++mi)
      a[mi] = *(const bfx8*)&As[cur][(wm * 64 + mi * 16 + (lane & 15)) * 32 + ko];
#pragma unroll
    for (int ni = 0; ni < 4; ++ni)
      b[ni] = *(const bfx8*)&Bs[cur][(wn * 64 + ni * 16 + (lane & 15)) * 32 + ko];
#pragma unroll
    for (int mi = 0; mi < 4; ++mi)
#pragma unroll
      for (int ni = 0; ni < 4; ++ni)
        acc[mi][ni] =
            __builtin_amdgcn_mfma_f32_16x16x32_bf16(a[mi], b[ni], acc[mi][ni], 0, 0, 0);
    __syncthreads();
    cur ^= 1;
  }

#pragma unroll
  for (int mi = 0; mi < 4; ++mi) {
    int row = m0 + wm * 64 + mi * 16 + ((lane >> 4) << 2);
#pragma unroll
    for (int ni = 0; ni < 4; ++ni) {
      int col = n0 + wn * 64 + ni * 16 + (lane & 15);
#pragma unroll
      for (int r = 0; r < 4; ++r) {
        float v = acc[mi][ni][r];
        if (OUTF32)
          ((float*)Cout)[(size_t)(row + r) * N + col] = v + bias[col];
        else
          ((uint16_t*)Cout)[(size_t)(row + r) * N + col] = f2b(v);
      }
    }
  }
}

// ---------------- flash attention v2: 64 q per wave, 2 groups share K/V reads ------
// 256 blocks: bh = did&63 (XCD-local heads, r5-proven: FETCH ~29MB), a = did>>6
// (0..3); block runs qb' = 7-a then a at QBLK=256 -> uniform 36 kv-tiles/block,
// 1 block/CU. 4 waves x 64 q (groups A=qw, B=qw+32). Per tile: QK both groups from
// the SAME kf fragments (8 ds_read_b128), PV both groups from the SAME vf (8) ->
// LDS traffic per unit work HALVED vs round 5. Distance-2 prefetch, K/V triple-
// buffered, counted vmcnt(4) raw barriers, cross-tile PV pipeline, in-reg softmax
// with defer-max. VGPR peak ~230 (fits (256,2)'s 256 budget; spill shows in
// WRITE_SIZE >> 16.4MB).
__global__ __launch_bounds__(256, 2) void flash_attn(const uint16_t* __restrict__ qkv,
                                                     uint16_t* __restrict__ attnb) {
  const int T = 2048, D3 = 3072;
  const float CSC = 0.125f * 1.44269504f;  // scale * log2(e)
  __shared__ alignas(16) uint16_t Ks[3][64 * 64];
  __shared__ alignas(16) uint16_t Vt[3][64 * 64];   // V^T: [hd][kv]

  int did = blockIdx.x;
  int bh = did & 63;
  int a = did >> 6;            // 0..3
  int b = bh >> 4, h = bh & 15;

  int tid = threadIdx.x, lane = tid & 63, wid = tid >> 6;
  int l31 = lane & 31, hi = lane >> 5;
  int swz = (lane & 7) << 3;

  size_t base = (size_t)b * T * D3;
  int hoff = h * 64;
  const uint16_t* kbase = &qkv[base + 1024 + hoff];
  const uint16_t* vbase = &qkv[base + 2048 + hoff];

  int krow = wid * 16 + (lane >> 3);
  int kc = ((lane & 7) << 3) ^ ((krow & 7) << 3);
  int vr = (tid & 31) * 2;
  int vc = (tid >> 5) * 8;

  for (int p = 0; p < 2; ++p) {
    int qb = (p == 0) ? (7 - a) : a;
    int q0 = qb << 8;                    // 256 q per block
    int qw = q0 + wid * 64;              // wave's 64 q rows
    int qA = qw, qB = qw + 32;
    int ntile = 4 * qb + 4;              // even, >= 4

    float mCA = -1e30f, lA = 0.f, mCB = -1e30f, lB = 0.f;
    f32x16 accA0 = {}, accA1 = {}, accB0 = {}, accB1 = {};
    bfx8 pfA[4], pfB[4];
    int smaxA_p = -1, smaxB_p = -1, vb_prev = 0;

    // Q frags (B-operand): col = q = qg + l31, k = hd = 16*h4 + 8*hi + j
    bfx8 qfA[4], qfB[4];
    {
      const uint16_t* qpA = &qkv[base + (size_t)(qA + l31) * D3 + hoff + 8 * hi];
      const uint16_t* qpB = &qkv[base + (size_t)(qB + l31) * D3 + hoff + 8 * hi];
#pragma unroll
      for (int h4 = 0; h4 < 4; ++h4) {
        qfA[h4] = *(const bfx8*)(qpA + 16 * h4);
        qfB[h4] = *(const bfx8*)(qpB + 16 * h4);
      }
    }

    uint4 vA0, vA1, vB0, vB1;   // two V register banks (tile parity)

    auto loadV = [&](int kv0, uint4& r0, uint4& r1) {
      r0 = *(const uint4*)&vbase[(size_t)(kv0 + vr) * D3 + vc];
      r1 = *(const uint4*)&vbase[(size_t)(kv0 + vr + 1) * D3 + vc];
    };
    auto stageK = [&](int buf, int kv0) {
      gld16(&kbase[(size_t)(kv0 + krow) * D3 + kc], &Ks[buf][wid * 1024]);
      gld16(&kbase[(size_t)(kv0 + krow + 8) * D3 + kc], &Ks[buf][wid * 1024 + 512]);
    };
    auto writeV = [&](int vb, const uint4& r0, const uint4& r1) {
      union { uint4 v; uint16_t u[8]; } x, y;
      x.v = r0; y.v = r1;
#pragma unroll
      for (int jj = 0; jj < 8; ++jj) {
        int hd = vc + jj;
        uint32_t pk = (uint32_t)x.u[jj] | ((uint32_t)y.u[jj] << 16);
        *(uint32_t*)&Vt[vb][hd * 64 + (vr ^ ((hd & 7) << 3))] = pk;
      }
    };
    auto doPV = [&]() {   // PV of previous tile, BOTH groups from shared vf
      const uint16_t* vp = &Vt[vb_prev][0];
      __builtin_amdgcn_s_setprio(1);
#pragma unroll
      for (int s = 0; s < 4; ++s) {
        if (s <= smaxB_p) {   // smaxB >= smaxA always
          bfx8 v0 = *(const bfx8*)&vp[l31 * 64 + ((16 * s + 8 * hi) ^ swz)];
          bfx8 v1 = *(const bfx8*)&vp[(32 + l31) * 64 + ((16 * s + 8 * hi) ^ swz)];
          if (s <= smaxA_p) {
            accA0 = __builtin_amdgcn_mfma_f32_32x32x16_bf16(v0, pfA[s], accA0, 0, 0, 0);
            accA1 = __builtin_amdgcn_mfma_f32_32x32x16_bf16(v1, pfA[s], accA1, 0, 0, 0);
          }
          accB0 = __builtin_amdgcn_mfma_f32_32x32x16_bf16(v0, pfB[s], accB0, 0, 0, 0);
          accB1 = __builtin_amdgcn_mfma_f32_32x32x16_bf16(v1, pfB[s], accB1, 0, 0, 0);
        }
      }
      __builtin_amdgcn_s_setprio(0);
    };

    // ---- prologue: stage tiles 0,1 fully; full drain once ----
    loadV(0, vA0, vA1);
    stageK(0, 0);
    writeV(0, vA0, vA1);
    loadV(64, vB0, vB1);
    stageK(1, 64);
    asm volatile("s_waitcnt vmcnt(0) lgkmcnt(0)" ::: "memory");
    __builtin_amdgcn_s_barrier();
    __builtin_amdgcn_sched_barrier(0);

    auto subiter = [&](int t, uint4& f0, uint4& f1, uint4& c0, uint4& c1) {
      int kv0 = t << 6;
      bool issue = (t + 2 < ntile);
      if (issue) {
        loadV((t + 2) << 6, f0, f1);
        stageK((t + 2) % 3, (t + 2) << 6);
      }
      bool actA = (kv0 <= qA), actB = (kv0 <= qB);
      int tmaxA = (qA > kv0) ? 2 : 1, tmaxB = (qB > kv0) ? 2 : 1;
      f32x16 sA0 = {}, sA1 = {}, sB0 = {}, sB1 = {};

      // ---- PV of PREVIOUS tile first (frees pf; before any rescale) ----
      if (smaxB_p >= 0) { doPV(); smaxA_p = -1; smaxB_p = -1; }

      if (actB) {
        // ---- S^T = K * Q^T for both groups from SHARED kf ----
        const uint16_t* kp = &Ks[t % 3][0];
        __builtin_amdgcn_s_setprio(1);
#pragma unroll
        for (int h4 = 0; h4 < 4; ++h4) {
          bfx8 kf0 = *(const bfx8*)&kp[l31 * 64 + ((16 * h4 + 8 * hi) ^ swz)];
          if (actA) sA0 = __builtin_amdgcn_mfma_f32_32x32x16_bf16(kf0, qfA[h4], sA0, 0, 0, 0);
          sB0 = __builtin_amdgcn_mfma_f32_32x32x16_bf16(kf0, qfB[h4], sB0, 0, 0, 0);
          if (actA) {   // tmaxB==2 <=> actA; kf1 only needed then
            bfx8 kf1 = *(const bfx8*)&kp[(32 + l31) * 64 + ((16 * h4 + 8 * hi) ^ swz)];
            if (tmaxA == 2) sA1 = __builtin_amdgcn_mfma_f32_32x32x16_bf16(kf1, qfA[h4], sA1, 0, 0, 0);
            sB1 = __builtin_amdgcn_mfma_f32_32x32x16_bf16(kf1, qfB[h4], sB1, 0, 0, 0);
          }
        }
        __builtin_amdgcn_s_setprio(0);

        // ---- softmax + pack, group by group (st freed between) ----
        auto softpack = [&](f32x16& s0, f32x16& s1, int tmaxg, int qg, float& mCg,
                            float& lg, f32x16& a0, f32x16& a1, bfx8* pfg) -> int {
          int q = qg + l31;
          float mx0 = -1e30f, mx1 = -1e30f;
          if (kv0 == qg) {
#pragma unroll
            for (int r = 0; r < 16; ++r) {
              int kv = kv0 + (r & 3) + 8 * (r >> 2) + 4 * hi;
              float v = s0[r];
              if (kv > q) v = -1e30f;
              s0[r] = v;
              mx0 = fmaxf(mx0, v);
            }
          } else {
#pragma unroll
            for (int r = 0; r < 16; ++r) mx0 = fmaxf(mx0, s0[r]);
          }
          if (tmaxg == 2) {
            if (kv0 + 32 == qg) {
#pragma unroll
              for (int r = 0; r < 16; ++r) {
                int kv = kv0 + 32 + (r & 3) + 8 * (r >> 2) + 4 * hi;
                float v = s1[r];
                if (kv > q) v = -1e30f;
                s1[r] = v;
                mx1 = fmaxf(mx1, v);
              }
            } else {
#pragma unroll
              for (int r = 0; r < 16; ++r) mx1 = fmaxf(mx1, s1[r]);
            }
          }
          float mS = fmaxf(mx0, mx1) * CSC;
          if (!__all(mS - mCg <= 8.0f)) {
            float mSp = fmaxf(mS, __shfl_xor(mS, 32));
            float mCn = fmaxf(mCg, mSp);
            float fac = __builtin_amdgcn_exp2f(mCg - mCn);
            mCg = mCn;
            lg *= fac;
            a0 *= fac;
            a1 *= fac;
          }
          float l0 = 0.f, l1 = 0.f, l2 = 0.f, l3 = 0.f;
#pragma unroll
          for (int r = 0; r < 16; r += 4) {
            float e0 = __builtin_amdgcn_exp2f(fmaf(s0[r], CSC, -mCg));
            float e1 = __builtin_amdgcn_exp2f(fmaf(s0[r + 1], CSC, -mCg));
            float e2 = __builtin_amdgcn_exp2f(fmaf(s0[r + 2], CSC, -mCg));
            float e3 = __builtin_amdgcn_exp2f(fmaf(s0[r + 3], CSC, -mCg));
            s0[r] = e0; s0[r + 1] = e1; s0[r + 2] = e2; s0[r + 3] = e3;
            l0 += e0; l1 += e1; l2 += e2; l3 += e3;
          }
          if (tmaxg == 2) {
#pragma unroll
            for (int r = 0; r < 16; r += 4) {
              float e0 = __builtin_amdgcn_exp2f(fmaf(s1[r], CSC, -mCg));
              float e1 = __builtin_amdgcn_exp2f(fmaf(s1[r + 1], CSC, -mCg));
              float e2 = __builtin_amdgcn_exp2f(fmaf(s1[r + 2], CSC, -mCg));
              float e3 = __builtin_amdgcn_exp2f(fmaf(s1[r + 3], CSC, -mCg));
              s1[r] = e0; s1[r + 1] = e1; s1[r + 2] = e2; s1[r + 3] = e3;
              l0 += e0; l1 += e1; l2 += e2; l3 += e3;
            }
          }
          lg += (l0 + l1) + (l2 + l3);

          int smax = (qg + 31 - kv0) >> 4;
          if (smax > 3) smax = 3;
#pragma unroll
          for (int s = 0; s < 4; ++s) {
            if (s <= smax) {
              int pb = 8 * (s & 1);
              uint32_t W0, W1, W2, W3;
              if (s < 2) {
                W0 = cvt_pk(s0[pb + 0], s0[pb + 1]);
                W1 = cvt_pk(s0[pb + 2], s0[pb + 3]);
                W2 = cvt_pk(s0[pb + 4], s0[pb + 5]);
                W3 = cvt_pk(s0[pb + 6], s0[pb + 7]);
              } else {
                W0 = cvt_pk(s1[pb + 0], s1[pb + 1]);
                W1 = cvt_pk(s1[pb + 2], s1[pb + 3]);
                W2 = cvt_pk(s1[pb + 4], s1[pb + 5]);
                W3 = cvt_pk(s1[pb + 6], s1[pb + 7]);
              }
              auto rA = __builtin_amdgcn_permlane32_swap(W0, W2, false, false);
              auto rB = __builtin_amdgcn_permlane32_swap(W1, W3, false, false);
              union { uint32_t u[4]; bfx8 v; } pk;
              pk.u[0] = rA[0]; pk.u[1] = rB[0]; pk.u[2] = rA[1]; pk.u[3] = rB[1];
              pfg[s] = pk.v;
            }
          }
          return smax;
        };

        if (actA) smaxA_p = softpack(sA0, sA1, tmaxA, qA, mCA, lA, accA0, accA1, pfA);
        smaxB_p = softpack(sB0, sB1, tmaxB, qB, mCB, lB, accB0, accB1, pfB);
        vb_prev = t % 3;
      }

      if (t + 1 < ntile) writeV((t + 1) % 3, c0, c1);

      if (issue)
        asm volatile("s_waitcnt vmcnt(4) lgkmcnt(0)" ::: "memory");
      else
        asm volatile("s_waitcnt vmcnt(0) lgkmcnt(0)" ::: "memory");
      __builtin_amdgcn_s_barrier();
      __builtin_amdgcn_sched_barrier(0);
    };

    for (int t = 0; t < ntile; t += 2) {
      subiter(t, vA0, vA1, vB0, vB1);
      subiter(t + 1, vB0, vB1, vA0, vA1);
    }
    if (smaxB_p >= 0) doPV();

    // ---- epilogue: merge l, normalize, transpose via LDS, coalesced store ----
    float ltA = lA + __shfl_xor(lA, 32);
    float ltB = lB + __shfl_xor(lB, 32);
    __syncthreads();   // all waves done with K/V LDS before overlay
    uint16_t* ow = ((uint16_t*)Ks) + wid * 4096;  // per-wave [64 q][64 hd] (spans Ks+Vt)
    float rlA = 1.0f / ltA, rlB = 1.0f / ltB;
#pragma unroll
    for (int g = 0; g < 2; ++g) {
      int prow = g * 32 + l31;
      float rl = g ? rlB : rlA;
#pragma unroll
      for (int f = 0; f < 2; ++f) {
#pragma unroll
        for (int r = 0; r < 16; r += 2) {
          int hd = 32 * f + (r & 3) + 8 * (r >> 2) + 4 * hi;
          float v0, v1;
          if (g == 0) { v0 = (f ? accA1[r] : accA0[r]); v1 = (f ? accA1[r + 1] : accA0[r + 1]); }
          else        { v0 = (f ? accB1[r] : accB0[r]); v1 = (f ? accB1[r + 1] : accB0[r + 1]); }
          *(uint32_t*)&ow[prow * 64 + (hd ^ ((l31 & 7) << 3))] = cvt_pk(v0 * rl, v1 * rl);
        }
      }
    }
    // wave-private region: no barrier needed between write and read
#pragma unroll
    for (int f2 = 0; f2 < 2; ++f2) {
      int row = f2 * 32 + (lane >> 1);
      int cb = (lane & 1) * 32;
      int q = q0 + wid * 64 + row;
      int rs = (row & 7) << 3;
      uint16_t* dst = &attnb[(size_t)(b * T + q) * 1024 + hoff + cb];
#pragma unroll
      for (int cc = 0; cc < 4; ++cc)
        *(uint4*)&dst[cc * 8] = *(const uint4*)&ow[row * 64 + ((cb + cc * 8) ^ rs)];
    }
    __syncthreads();   // epilogue reads done before next part restages Ks
  }
}

// ---------------- host ----------------
extern "C" void kernel_launch(void* const* d_in, const int* in_sizes, int n_in,
                              void* d_out, int out_size, void* d_ws, size_t ws_size,
                              hipStream_t stream) {
  const float* x = (const float*)d_in[0];
  const float* qkv_w = (const float*)d_in[1];
  const float* out_w = (const float*)d_in[2];
  const float* out_b = (const float*)d_in[3];
  float* out = (float*)d_out;

  char* ws = (char*)d_ws;
  uint16_t* xb    = (uint16_t*)(ws);
  uint16_t* qkvb  = (uint16_t*)(ws + 16777216);
  uint16_t* attnb = (uint16_t*)(ws + 67108864);
  uint16_t* wqkvb = (uint16_t*)(ws + 83886080);
  uint16_t* wob   = (uint16_t*)(ws + 90177536);

  cvt_all<<<6144, 256, 0, stream>>>(x, qkv_w, out_w, xb, wqkvb, wob);

  // qkv = x @ qkv_w^T : M=8192 N=3072 K=1024, 128^2 tiles -> grid 64*24=1536
  gemm_bt<0><<<1536, 256, 0, stream>>>(xb, wqkvb, (void*)qkvb, nullptr,
                                       8192, 3072, 1024, 24, 1536);
  flash_attn<<<256, 256, 0, stream>>>(qkvb, attnb);
  // out = attn @ out_w^T + b : M=8192 N=1024 K=1024 -> grid 512
  gemm_bt<1><<<512, 256, 0, stream>>>(attnb, wob, (void*)out, out_b,
                                      8192, 1024, 1024, 8, 512);
}

// Round 11
// 188.851 us; speedup vs baseline: 1.2566x; 1.2566x over previous
//
#include <hip/hip_runtime.h>
#include <stdint.h>

// Shapes (fixed): x [4,2048,1024] f32, qkv_w [3072,1024] f32, out_w [1024,1024] f32,
// out_b [1024] f32, out [4,2048,1024] f32.
// Pipeline: cvt->bf16 (fused), gemm8p qkv = x@qkv_w^T (256^2 tile, BK=64, 4-phase/
// K-tile interleave, counted vmcnt(8), m201-style), flash attn (round-5 config),
// gemm_bt out = attn@out_w^T + b (128^2).

typedef __bf16 bfx8 __attribute__((ext_vector_type(8)));
typedef float f32x4 __attribute__((ext_vector_type(4)));
typedef float f32x16 __attribute__((ext_vector_type(16)));

__device__ __forceinline__ uint16_t f2b(float f) {
  uint32_t u = __float_as_uint(f);
  u += 0x7fff + ((u >> 16) & 1);   // RNE
  return (uint16_t)(u >> 16);
}

__device__ __forceinline__ uint32_t cvt_pk(float lo, float hi) {
  uint32_t r;
  asm("v_cvt_pk_bf16_f32 %0, %1, %2" : "=v"(r) : "v"(lo), "v"(hi));
  return r;
}

__device__ __forceinline__ void gld16(const void* g, void* l) {
  __builtin_amdgcn_global_load_lds((const __attribute__((address_space(1))) void*)g,
                                   (__attribute__((address_space(3))) void*)l,
                                   16, 0, 0);
}

// ---------------- fused f32 -> bf16 convert (8 elems/thread, 3 tensors) -----------
__global__ __launch_bounds__(256) void cvt_all(const float* __restrict__ x,
                                               const float* __restrict__ w1,
                                               const float* __restrict__ w2,
                                               uint16_t* __restrict__ xb,
                                               uint16_t* __restrict__ w1b,
                                               uint16_t* __restrict__ w2b) {
  int i = blockIdx.x * 256 + threadIdx.x;
  const float* in;
  uint16_t* out;
  if (i < 1048576) { in = x; out = xb; }
  else if (i < 1048576 + 393216) { in = w1; out = w1b; i -= 1048576; }
  else { in = w2; out = w2b; i -= 1048576 + 393216; }
  float4 a = ((const float4*)in)[2 * i];
  float4 b = ((const float4*)in)[2 * i + 1];
  union { uint16_t u[8]; uint4 v; } pk;
  pk.u[0] = f2b(a.x); pk.u[1] = f2b(a.y); pk.u[2] = f2b(a.z); pk.u[3] = f2b(a.w);
  pk.u[4] = f2b(b.x); pk.u[5] = f2b(b.y); pk.u[6] = f2b(b.z); pk.u[7] = f2b(b.w);
  ((uint4*)out)[i] = pk.v;
}

// ---------------- gemm8p: C[M,N] = A[M,K]*B[N,K]^T, bf16 out (8-phase 256^2) ------
// 256x256 tile, BK=64, 512 threads (8 waves 2x4; wave out = 128x64 = 8mi x 4ni).
// LDS: As/Bs[2][256x64] = 128KB (double-buffered by K-tile parity).
// Per K-tile t, 4 phases, each {ds_read subtile; stage; s_barrier; setprio1;
// 16 MFMA (one quadrant x K=64); setprio0; s_barrier}:
//   P1: read a[mi0-3]+b[ni0-1] -> Q00.   P2: read b[ni2-3] -> Q01.
//   P3: read a2[mi4-7], STAGE B(t+2) -> Q10.   P4: STAGE A(t+2), vmcnt(8) -> Q11.
// vmcnt(8) = tile t+2's 8 loads stay in flight; forces tile t+1 landed (read next
// group). WAR: B region staged P3, last read P2; A staged P4, last read P3 - all
// barrier-separated. t=nt-2: vmcnt(0) (forces tile nt-1; no new stages).
// Swizzle: elem(r,c) at r*64 + (c ^ ((r&7)*8)); staged via pre-swizzled global col.
__global__ __launch_bounds__(512, 2) void gemm8p(const uint16_t* __restrict__ A,
                                                 const uint16_t* __restrict__ B,
                                                 uint16_t* __restrict__ C,
                                                 int M, int N, int K, int nbx, int nwg) {
  __shared__ alignas(16) uint16_t As[2][256 * 64];
  __shared__ alignas(16) uint16_t Bs[2][256 * 64];

  int did = blockIdx.x;
  int wg = (did & 7) * (nwg >> 3) + (did >> 3);   // XCD swizzle (nwg % 8 == 0)
  int bx = wg % nbx, by = wg / nbx;
  int m0 = by * 256, n0 = bx * 256;

  int tid = threadIdx.x, lane = tid & 63, wid = tid >> 6;
  int wm = wid >> 2, wn = wid & 3;
  int l15 = lane & 15;
  int ko = (lane >> 4) * 8;
  int sw = (l15 & 7) * 8;            // read swizzle term (row&7 == l15&7)

  int srow = lane >> 3;              // staging: row-in-8
  int scol = ((lane & 7) ^ srow) * 8;  // pre-swizzled global col block

  f32x4 acc[8][4] = {};

  auto stageA = [&](int buf, int t) {
    int k0 = t * 64;
#pragma unroll
    for (int i = 0; i < 4; ++i) {
      int r = wid * 32 + i * 8;
      gld16(&A[(size_t)(m0 + r + srow) * K + k0 + scol], &As[buf][r * 64]);
    }
  };
  auto stageB = [&](int buf, int t) {
    int k0 = t * 64;
#pragma unroll
    for (int i = 0; i < 4; ++i) {
      int r = wid * 32 + i * 8;
      gld16(&B[(size_t)(n0 + r + srow) * K + k0 + scol], &Bs[buf][r * 64]);
    }
  };

  // prologue: tiles 0 (buf0) and 1 (buf1); vmcnt(8) -> tile 0 landed
  stageA(0, 0); stageB(0, 0);
  stageA(1, 1); stageB(1, 1);
  asm volatile("s_waitcnt vmcnt(8)" ::: "memory");
  __builtin_amdgcn_s_barrier();
  __builtin_amdgcn_sched_barrier(0);

  int nt = K >> 6;   // 16
  for (int t = 0; t < nt; ++t) {
    int buf = t & 1;
    const uint16_t* ap = &As[buf][0];
    const uint16_t* bp = &Bs[buf][0];
    bfx8 a[4][2], b01[2][2], b23[2][2], a2[4][2];

    // ---- P1: read A-low (8) + B-low (4); MFMA Q00 ----
#pragma unroll
    for (int mi = 0; mi < 4; ++mi)
#pragma unroll
      for (int kk = 0; kk < 2; ++kk) {
        int r = wm * 128 + mi * 16 + l15;
        a[mi][kk] = *(const bfx8*)&ap[r * 64 + ((kk * 32 + ko) ^ sw)];
      }
#pragma unroll
    for (int ni = 0; ni < 2; ++ni)
#pragma unroll
      for (int kk = 0; kk < 2; ++kk) {
        int r = wn * 64 + ni * 16 + l15;
        b01[ni][kk] = *(const bfx8*)&bp[r * 64 + ((kk * 32 + ko) ^ sw)];
      }
    __builtin_amdgcn_s_barrier();
    __builtin_amdgcn_s_setprio(1);
#pragma unroll
    for (int mi = 0; mi < 4; ++mi)
#pragma unroll
      for (int ni = 0; ni < 2; ++ni)
#pragma unroll
        for (int kk = 0; kk < 2; ++kk)
          acc[mi][ni] = __builtin_amdgcn_mfma_f32_16x16x32_bf16(a[mi][kk], b01[ni][kk],
                                                                acc[mi][ni], 0, 0, 0);
    __builtin_amdgcn_s_setprio(0);
    __builtin_amdgcn_s_barrier();

    // ---- P2: read B-high (4); MFMA Q01 ----
#pragma unroll
    for (int ni = 0; ni < 2; ++ni)
#pragma unroll
      for (int kk = 0; kk < 2; ++kk) {
        int r = wn * 64 + (ni + 2) * 16 + l15;
        b23[ni][kk] = *(const bfx8*)&bp[r * 64 + ((kk * 32 + ko) ^ sw)];
      }
    __builtin_amdgcn_s_barrier();
    __builtin_amdgcn_s_setprio(1);
#pragma unroll
    for (int mi = 0; mi < 4; ++mi)
#pragma unroll
      for (int ni = 0; ni < 2; ++ni)
#pragma unroll
        for (int kk = 0; kk < 2; ++kk)
          acc[mi][ni + 2] = __builtin_amdgcn_mfma_f32_16x16x32_bf16(a[mi][kk], b23[ni][kk],
                                                                    acc[mi][ni + 2], 0, 0, 0);
    __builtin_amdgcn_s_setprio(0);
    __builtin_amdgcn_s_barrier();

    // ---- P3: read A-high (8); stage B(t+2); MFMA Q10 ----
#pragma unroll
    for (int mi = 0; mi < 4; ++mi)
#pragma unroll
      for (int kk = 0; kk < 2; ++kk) {
        int r = wm * 128 + (mi + 4) * 16 + l15;
        a2[mi][kk] = *(const bfx8*)&ap[r * 64 + ((kk * 32 + ko) ^ sw)];
      }
    if (t + 2 < nt) stageB(buf, t + 2);
    __builtin_amdgcn_s_barrier();
    __builtin_amdgcn_s_setprio(1);
#pragma unroll
    for (int mi = 0; mi < 4; ++mi)
#pragma unroll
      for (int ni = 0; ni < 2; ++ni)
#pragma unroll
        for (int kk = 0; kk < 2; ++kk)
          acc[mi + 4][ni] = __builtin_amdgcn_mfma_f32_16x16x32_bf16(a2[mi][kk], b01[ni][kk],
                                                                    acc[mi + 4][ni], 0, 0, 0);
    __builtin_amdgcn_s_setprio(0);
    __builtin_amdgcn_s_barrier();

    // ---- P4: stage A(t+2); counted vmcnt; MFMA Q11 ----
    if (t + 2 < nt) {
      stageA(buf, t + 2);
      asm volatile("s_waitcnt vmcnt(8)" ::: "memory");   // t+2's 8 in flight; t+1 landed
    } else if (t + 2 == nt) {
      asm volatile("s_waitcnt vmcnt(0)" ::: "memory");   // force tile nt-1
    }
    __builtin_amdgcn_sched_barrier(0);
    __builtin_amdgcn_s_barrier();
    __builtin_amdgcn_s_setprio(1);
#pragma unroll
    for (int mi = 0; mi < 4; ++mi)
#pragma unroll
      for (int ni = 0; ni < 2; ++ni)
#pragma unroll
        for (int kk = 0; kk < 2; ++kk)
          acc[mi + 4][ni + 2] = __builtin_amdgcn_mfma_f32_16x16x32_bf16(a2[mi][kk], b23[ni][kk],
                                                                        acc[mi + 4][ni + 2], 0, 0, 0);
    __builtin_amdgcn_s_setprio(0);
    __builtin_amdgcn_s_barrier();
  }

  // epilogue: C/D layout col=lane&15, row=(lane>>4)*4+r
#pragma unroll
  for (int mi = 0; mi < 8; ++mi) {
    int row = m0 + wm * 128 + mi * 16 + ((lane >> 4) << 2);
#pragma unroll
    for (int ni = 0; ni < 4; ++ni) {
      int col = n0 + wn * 64 + ni * 16 + l15;
#pragma unroll
      for (int r = 0; r < 4; ++r)
        C[(size_t)(row + r) * N + col] = f2b(acc[mi][ni][r]);
    }
  }
}

// ---------------- GEMM 128^2 (out-proj): C = A*B^T + bias, f32 out ----------------
template <int OUTF32>
__global__ __launch_bounds__(256) void gemm_bt(const uint16_t* __restrict__ A,
                                               const uint16_t* __restrict__ B,
                                               void* __restrict__ Cout,
                                               const float* __restrict__ bias,
                                               int M, int N, int K, int nbx, int nwg) {
  __shared__ alignas(16) uint16_t As[2][128 * 32];
  __shared__ alignas(16) uint16_t Bs[2][128 * 32];

  int did = blockIdx.x;
  int wg = (did & 7) * (nwg >> 3) + (did >> 3);
  int bx = wg % nbx, by = wg / nbx;
  int m0 = by * 128, n0 = bx * 128;

  int tid = threadIdx.x;
  int lane = tid & 63, wid = tid >> 6;
  int wm = wid >> 1, wn = wid & 1;

  int rs = wid * 16 + (lane >> 2);
  int cs = (lane & 3) * 8;

  f32x4 acc[4][4] = {};

  auto stage = [&](int buf, int kt) {
    int k0 = kt * 32;
    gld16(&A[(size_t)(m0 + rs) * K + k0 + cs],      &As[buf][wid * 512]);
    gld16(&A[(size_t)(m0 + rs + 64) * K + k0 + cs], &As[buf][wid * 512 + 2048]);
    gld16(&B[(size_t)(n0 + rs) * K + k0 + cs],      &Bs[buf][wid * 512]);
    gld16(&B[(size_t)(n0 + rs + 64) * K + k0 + cs], &Bs[buf][wid * 512 + 2048]);
  };

  stage(0, 0);
  __syncthreads();

  int nk = K >> 5;
  int cur = 0;
  int ko = (lane >> 4) * 8;
  for (int kt = 0; kt < nk; ++kt) {
    if (kt + 1 < nk) stage(cur ^ 1, kt + 1);
    bfx8 a[4], b[4];
#pragma unroll
    for (int mi = 0; mi < 4; ++mi)
      a[mi] = *(const bfx8*)&As[cur][(wm * 64 + mi * 16 + (lane & 15)) * 32 + ko];
#pragma unroll
    for (int ni = 0; ni < 4; ++ni)
      b[ni] = *(const bfx8*)&Bs[cur][(wn * 64 + ni * 16 + (lane & 15)) * 32 + ko];
#pragma unroll
    for (int mi = 0; mi < 4; ++mi)
#pragma unroll
      for (int ni = 0; ni < 4; ++ni)
        acc[mi][ni] =
            __builtin_amdgcn_mfma_f32_16x16x32_bf16(a[mi], b[ni], acc[mi][ni], 0, 0, 0);
    __syncthreads();
    cur ^= 1;
  }

#pragma unroll
  for (int mi = 0; mi < 4; ++mi) {
    int row = m0 + wm * 64 + mi * 16 + ((lane >> 4) << 2);
#pragma unroll
    for (int ni = 0; ni < 4; ++ni) {
      int col = n0 + wn * 64 + ni * 16 + (lane & 15);
#pragma unroll
      for (int r = 0; r < 4; ++r) {
        float v = acc[mi][ni][r];
        if (OUTF32)
          ((float*)Cout)[(size_t)(row + r) * N + col] = v + bias[col];
        else
          ((uint16_t*)Cout)[(size_t)(row + r) * N + col] = f2b(v);
      }
    }
  }
}

// ---------------- flash attention (causal), pipelined 32x32 S^T / O^T ----------
// ROUND-5 CONFIG (best measured): 512 UNIFORM blocks: bh = d&63 (XCD locality),
// a = d>>6; block runs qb = 15-a then a -> exactly 34 kv-tiles. 4 waves x 32 q.
// Distance-2 prefetch; K triple-buffered LDS, V triple-buffered via 2-bank register
// staging. Raw s_barrier with COUNTED vmcnt(4). launch_bounds (256,2) (NOT (256,3):
// r6 spill storm; NOT 64q/wave: r10 spill at forced 128 VGPR).
__global__ __launch_bounds__(256, 2) void flash_attn(const uint16_t* __restrict__ qkv,
                                                     uint16_t* __restrict__ attnb) {
  const int T = 2048, D3 = 3072;
  const float CSC = 0.125f * 1.44269504f;  // scale * log2(e)
  __shared__ alignas(16) uint16_t Ks[3][64 * 64];
  __shared__ alignas(16) uint16_t Vt[3][64 * 64];   // V^T: [hd][kv]

  int d = blockIdx.x;
  int bh = d & 63;
  int a = d >> 6;              // 0..7
  int b = bh >> 4, h = bh & 15;

  int tid = threadIdx.x, lane = tid & 63, wid = tid >> 6;
  int l31 = lane & 31, hi = lane >> 5;
  int swz = (lane & 7) << 3;

  size_t base = (size_t)b * T * D3;
  int hoff = h * 64;
  const uint16_t* kbase = &qkv[base + 1024 + hoff];
  const uint16_t* vbase = &qkv[base + 2048 + hoff];

  int krow = wid * 16 + (lane >> 3);
  int kc = ((lane & 7) << 3) ^ ((krow & 7) << 3);
  int vr = (tid & 31) * 2;
  int vc = (tid >> 5) * 8;

  for (int p = 0; p < 2; ++p) {
    int qb = (p == 0) ? (15 - a) : a;   // long part first
    int q0 = qb << 7;
    int qw = q0 + wid * 32;
    int ntile = 2 * qb + 2;             // even

    float mC = -1e30f, l_r = 0.f;       // l_r: per-lane partial
    f32x16 acc0 = {}, acc1 = {};
    bfx8 pf[4];
    int smax_prev = -1, vb_prev = 0;

    // Q frags (B-operand): col=q=l31, k = hd = 16*h4 + 8*hi + j
    bfx8 qf[4];
    {
      const uint16_t* qp = &qkv[base + (size_t)(qw + l31) * D3 + hoff + 8 * hi];
#pragma unroll
      for (int h4 = 0; h4 < 4; ++h4) qf[h4] = *(const bfx8*)(qp + 16 * h4);
    }

    uint4 vA0, vA1, vB0, vB1;   // two V register banks (tile parity)

    auto loadV = [&](int kv0, uint4& r0, uint4& r1) {
      r0 = *(const uint4*)&vbase[(size_t)(kv0 + vr) * D3 + vc];
      r1 = *(const uint4*)&vbase[(size_t)(kv0 + vr + 1) * D3 + vc];
    };
    auto stageK = [&](int buf, int kv0) {
      gld16(&kbase[(size_t)(kv0 + krow) * D3 + kc], &Ks[buf][wid * 1024]);
      gld16(&kbase[(size_t)(kv0 + krow + 8) * D3 + kc], &Ks[buf][wid * 1024 + 512]);
    };
    auto writeV = [&](int vb, const uint4& r0, const uint4& r1) {
      union { uint4 v; uint16_t u[8]; } x, y;
      x.v = r0; y.v = r1;
#pragma unroll
      for (int jj = 0; jj < 8; ++jj) {
        int hd = vc + jj;
        uint32_t pk = (uint32_t)x.u[jj] | ((uint32_t)y.u[jj] << 16);
        *(uint32_t*)&Vt[vb][hd * 64 + (vr ^ ((hd & 7) << 3))] = pk;
      }
    };
    auto doPV = [&]() {
      const uint16_t* vp = &Vt[vb_prev][0];
      __builtin_amdgcn_s_setprio(1);
#pragma unroll
      for (int s = 0; s < 4; ++s) {
        if (s <= smax_prev) {
          bfx8 v0 = *(const bfx8*)&vp[l31 * 64 + ((16 * s + 8 * hi) ^ swz)];
          acc0 = __builtin_amdgcn_mfma_f32_32x32x16_bf16(v0, pf[s], acc0, 0, 0, 0);
          bfx8 v1 = *(const bfx8*)&vp[(32 + l31) * 64 + ((16 * s + 8 * hi) ^ swz)];
          acc1 = __builtin_amdgcn_mfma_f32_32x32x16_bf16(v1, pf[s], acc1, 0, 0, 0);
        }
      }
      __builtin_amdgcn_s_setprio(0);
    };

    // ---- prologue: stage tiles 0,1 fully; full drain once ----
    loadV(0, vA0, vA1);
    stageK(0, 0);
    writeV(0, vA0, vA1);
    loadV(64, vB0, vB1);
    stageK(1, 64);
    asm volatile("s_waitcnt vmcnt(0) lgkmcnt(0)" ::: "memory");
    __builtin_amdgcn_s_barrier();
    __builtin_amdgcn_sched_barrier(0);

    auto subiter = [&](int t, uint4& f0, uint4& f1, uint4& c0, uint4& c1) {
      int kv0 = t << 6;
      bool issue = (t + 2 < ntile);
      if (issue) {
        loadV((t + 2) << 6, f0, f1);
        stageK((t + 2) % 3, (t + 2) << 6);
      }
      bool active = (kv0 <= qw);
      int tmax = (qw > kv0) ? 2 : 1;
      f32x16 st0 = {}, st1 = {};
      if (active) {
        const uint16_t* kp = &Ks[t % 3][0];
        __builtin_amdgcn_s_setprio(1);
#pragma unroll
        for (int h4 = 0; h4 < 4; ++h4) {
          bfx8 kf0 = *(const bfx8*)&kp[l31 * 64 + ((16 * h4 + 8 * hi) ^ swz)];
          st0 = __builtin_amdgcn_mfma_f32_32x32x16_bf16(kf0, qf[h4], st0, 0, 0, 0);
          if (tmax == 2) {
            bfx8 kf1 = *(const bfx8*)&kp[(32 + l31) * 64 + ((16 * h4 + 8 * hi) ^ swz)];
            st1 = __builtin_amdgcn_mfma_f32_32x32x16_bf16(kf1, qf[h4], st1, 0, 0, 0);
          }
        }
        __builtin_amdgcn_s_setprio(0);
      }

      if (smax_prev >= 0) { doPV(); smax_prev = -1; }

      if (active) {
        int q = qw + l31;
        float mx0 = -1e30f, mx1 = -1e30f;
        if (kv0 == qw) {
#pragma unroll
          for (int r = 0; r < 16; ++r) {
            int kv = kv0 + (r & 3) + 8 * (r >> 2) + 4 * hi;
            float v = st0[r];
            if (kv > q) v = -1e30f;
            st0[r] = v;
            mx0 = fmaxf(mx0, v);
          }
        } else {
#pragma unroll
          for (int r = 0; r < 16; ++r) mx0 = fmaxf(mx0, st0[r]);
        }
        if (tmax == 2) {
          if (kv0 + 32 == qw) {
#pragma unroll
            for (int r = 0; r < 16; ++r) {
              int kv = kv0 + 32 + (r & 3) + 8 * (r >> 2) + 4 * hi;
              float v = st1[r];
              if (kv > q) v = -1e30f;
              st1[r] = v;
              mx1 = fmaxf(mx1, v);
            }
          } else {
#pragma unroll
            for (int r = 0; r < 16; ++r) mx1 = fmaxf(mx1, st1[r]);
          }
        }
        float mS = fmaxf(mx0, mx1) * CSC;
        if (!__all(mS - mC <= 8.0f)) {
          float mSp = fmaxf(mS, __shfl_xor(mS, 32));
          float mCn = fmaxf(mC, mSp);
          float fac = __builtin_amdgcn_exp2f(mC - mCn);
          mC = mCn;
          l_r *= fac;
          acc0 *= fac;
          acc1 *= fac;
        }
        float l0 = 0.f, l1 = 0.f, l2 = 0.f, l3 = 0.f;
#pragma unroll
        for (int r = 0; r < 16; r += 4) {
          float e0 = __builtin_amdgcn_exp2f(fmaf(st0[r], CSC, -mC));
          float e1 = __builtin_amdgcn_exp2f(fmaf(st0[r + 1], CSC, -mC));
          float e2 = __builtin_amdgcn_exp2f(fmaf(st0[r + 2], CSC, -mC));
          float e3 = __builtin_amdgcn_exp2f(fmaf(st0[r + 3], CSC, -mC));
          st0[r] = e0; st0[r + 1] = e1; st0[r + 2] = e2; st0[r + 3] = e3;
          l0 += e0; l1 += e1; l2 += e2; l3 += e3;
        }
        if (tmax == 2) {
#pragma unroll
          for (int r = 0; r < 16; r += 4) {
            float e0 = __builtin_amdgcn_exp2f(fmaf(st1[r], CSC, -mC));
            float e1 = __builtin_amdgcn_exp2f(fmaf(st1[r + 1], CSC, -mC));
            float e2 = __builtin_amdgcn_exp2f(fmaf(st1[r + 2], CSC, -mC));
            float e3 = __builtin_amdgcn_exp2f(fmaf(st1[r + 3], CSC, -mC));
            st1[r] = e0; st1[r + 1] = e1; st1[r + 2] = e2; st1[r + 3] = e3;
            l0 += e0; l1 += e1; l2 += e2; l3 += e3;
          }
        }
        l_r += (l0 + l1) + (l2 + l3);

        int smax = (qw + 31 - kv0) >> 4;
        if (smax > 3) smax = 3;
#pragma unroll
        for (int s = 0; s < 4; ++s) {
          if (s <= smax) {
            int pb = 8 * (s & 1);
            uint32_t W0, W1, W2, W3;
            if (s < 2) {
              W0 = cvt_pk(st0[pb + 0], st0[pb + 1]);
              W1 = cvt_pk(st0[pb + 2], st0[pb + 3]);
              W2 = cvt_pk(st0[pb + 4], st0[pb + 5]);
              W3 = cvt_pk(st0[pb + 6], st0[pb + 7]);
            } else {
              W0 = cvt_pk(st1[pb + 0], st1[pb + 1]);
              W1 = cvt_pk(st1[pb + 2], st1[pb + 3]);
              W2 = cvt_pk(st1[pb + 4], st1[pb + 5]);
              W3 = cvt_pk(st1[pb + 6], st1[pb + 7]);
            }
            auto rA = __builtin_amdgcn_permlane32_swap(W0, W2, false, false);
            auto rB = __builtin_amdgcn_permlane32_swap(W1, W3, false, false);
            union { uint32_t u[4]; bfx8 v; } pk;
            pk.u[0] = rA[0]; pk.u[1] = rB[0]; pk.u[2] = rA[1]; pk.u[3] = rB[1];
            pf[s] = pk.v;
          }
        }
        smax_prev = smax;
        vb_prev = t % 3;
      }

      if (t + 1 < ntile) writeV((t + 1) % 3, c0, c1);

      if (issue)
        asm volatile("s_waitcnt vmcnt(4) lgkmcnt(0)" ::: "memory");
      else
        asm volatile("s_waitcnt vmcnt(0) lgkmcnt(0)" ::: "memory");
      __builtin_amdgcn_s_barrier();
      __builtin_amdgcn_sched_barrier(0);
    };

    for (int t = 0; t < ntile; t += 2) {
      subiter(t, vA0, vA1, vB0, vB1);
      subiter(t + 1, vB0, vB1, vA0, vA1);
    }
    if (smax_prev >= 0) doPV();

    // ---- epilogue ----
    float l_tot = l_r + __shfl_xor(l_r, 32);
    __syncthreads();
    uint16_t* ow = ((uint16_t*)Ks) + wid * 2048;
    float rl = 1.0f / l_tot;
#pragma unroll
    for (int f = 0; f < 2; ++f) {
#pragma unroll
      for (int r = 0; r < 16; r += 2) {
        int hd = 32 * f + (r & 3) + 8 * (r >> 2) + 4 * hi;
        float v0 = (f ? acc1[r] : acc0[r]) * rl;
        float v1 = (f ? acc1[r + 1] : acc0[r + 1]) * rl;
        *(uint32_t*)&ow[l31 * 64 + (hd ^ ((l31 & 7) << 3))] = cvt_pk(v0, v1);
      }
    }
    int row = lane >> 1, cb = (lane & 1) * 32;
    int q = q0 + wid * 32 + row;
    int rs = (row & 7) << 3;
    uint16_t* dst = &attnb[(size_t)(b * T + q) * 1024 + hoff + cb];
#pragma unroll
    for (int cc = 0; cc < 4; ++cc)
      *(uint4*)&dst[cc * 8] = *(const uint4*)&ow[row * 64 + ((cb + cc * 8) ^ rs)];
    __syncthreads();
  }
}

// ---------------- host ----------------
extern "C" void kernel_launch(void* const* d_in, const int* in_sizes, int n_in,
                              void* d_out, int out_size, void* d_ws, size_t ws_size,
                              hipStream_t stream) {
  const float* x = (const float*)d_in[0];
  const float* qkv_w = (const float*)d_in[1];
  const float* out_w = (const float*)d_in[2];
  const float* out_b = (const float*)d_in[3];
  float* out = (float*)d_out;

  char* ws = (char*)d_ws;
  uint16_t* xb    = (uint16_t*)(ws);
  uint16_t* qkvb  = (uint16_t*)(ws + 16777216);
  uint16_t* attnb = (uint16_t*)(ws + 67108864);
  uint16_t* wqkvb = (uint16_t*)(ws + 83886080);
  uint16_t* wob   = (uint16_t*)(ws + 90177536);

  cvt_all<<<6144, 256, 0, stream>>>(x, qkv_w, out_w, xb, wqkvb, wob);

  // qkv = x @ qkv_w^T : M=8192 N=3072 K=1024, 256^2 tiles -> grid 32*12=384
  gemm8p<<<384, 512, 0, stream>>>(xb, wqkvb, qkvb, 8192, 3072, 1024, 12, 384);
  flash_attn<<<512, 256, 0, stream>>>(qkvb, attnb);
  // out = attn @ out_w^T + b : M=8192 N=1024 K=1024 -> grid 512
  gemm_bt<1><<<512, 256, 0, stream>>>(attnb, wob, (void*)out, out_b,
                                      8192, 1024, 1024, 8, 512);
}

// Round 12
// 182.750 us; speedup vs baseline: 1.2985x; 1.0334x over previous
//
#include <hip/hip_runtime.h>
#include <stdint.h>

// Shapes (fixed): x [4,2048,1024] f32, qkv_w [3072,1024] f32, out_w [1024,1024] f32,
// out_b [1024] f32, out [4,2048,1024] f32.
// Pipeline: cvt->bf16 (fused), gemm8p<NI=3> qkv (256x192 tile -> grid 512 = 2 FULL
// rounds of 256 CUs; r11's 256x256 grid 384 wasted 25% on the half-empty round),
// flash attn (round-5 config, proven 89us), gemm8p<NI=2,f32+bias> out (256x128 ->
// grid 256 = 1 full round).

typedef __bf16 bfx8 __attribute__((ext_vector_type(8)));
typedef float f32x4 __attribute__((ext_vector_type(4)));
typedef float f32x16 __attribute__((ext_vector_type(16)));

__device__ __forceinline__ uint16_t f2b(float f) {
  uint32_t u = __float_as_uint(f);
  u += 0x7fff + ((u >> 16) & 1);   // RNE
  return (uint16_t)(u >> 16);
}

__device__ __forceinline__ uint32_t cvt_pk(float lo, float hi) {
  uint32_t r;
  asm("v_cvt_pk_bf16_f32 %0, %1, %2" : "=v"(r) : "v"(lo), "v"(hi));
  return r;
}

__device__ __forceinline__ void gld16(const void* g, void* l) {
  __builtin_amdgcn_global_load_lds((const __attribute__((address_space(1))) void*)g,
                                   (__attribute__((address_space(3))) void*)l,
                                   16, 0, 0);
}

// ---------------- fused f32 -> bf16 convert (8 elems/thread, 3 tensors) -----------
__global__ __launch_bounds__(256) void cvt_all(const float* __restrict__ x,
                                               const float* __restrict__ w1,
                                               const float* __restrict__ w2,
                                               uint16_t* __restrict__ xb,
                                               uint16_t* __restrict__ w1b,
                                               uint16_t* __restrict__ w2b) {
  int i = blockIdx.x * 256 + threadIdx.x;
  const float* in;
  uint16_t* out;
  if (i < 1048576) { in = x; out = xb; }
  else if (i < 1048576 + 393216) { in = w1; out = w1b; i -= 1048576; }
  else { in = w2; out = w2b; i -= 1048576 + 393216; }
  float4 a = ((const float4*)in)[2 * i];
  float4 b = ((const float4*)in)[2 * i + 1];
  union { uint16_t u[8]; uint4 v; } pk;
  pk.u[0] = f2b(a.x); pk.u[1] = f2b(a.y); pk.u[2] = f2b(a.z); pk.u[3] = f2b(a.w);
  pk.u[4] = f2b(b.x); pk.u[5] = f2b(b.y); pk.u[6] = f2b(b.z); pk.u[7] = f2b(b.w);
  ((uint4*)out)[i] = pk.v;
}

// ---------------- gemm8p<NI,OUTF32>: C[M,N] = A[M,K]*B[N,K]^T (+bias) -------------
// BM=256, BN=64*NI, BK=64, 512 threads (8 waves 2x4; wave out = 128 x NI*16).
// LDS: As[2][256x64] + Bs[2][64*NI x 64], double-buffered by K-tile parity.
// Per K-tile t, 4 phases {reads/stages; s_barrier; setprio1; MFMA quadrant;
// setprio0; s_barrier}: P1 a-low+b-G0 -> Q(lo,G0); P2 b-G1 -> Q(lo,G1);
// P3 a-high + STAGE B(t+2) -> Q(hi,G0); P4 STAGE A(t+2) + vmcnt(4+NI) -> Q(hi,G1).
// Counted vmcnt(4+NI): tile t+2's loads stay in flight, tile t+1 forced landed.
// WAR/RAW invariants identical to the r11-proven kernel (same parity scheme).
// Swizzle: elem(r,c) at r*64 + (c ^ ((r&7)*8)); staged via pre-swizzled global col.
template <int NI, int OUTF32>
__global__ __launch_bounds__(512, 2) void gemm8p(const uint16_t* __restrict__ A,
                                                 const uint16_t* __restrict__ B,
                                                 void* __restrict__ Cout,
                                                 const float* __restrict__ bias,
                                                 int M, int N, int K, int nbx, int nwg) {
  constexpr int G0 = (NI + 1) / 2;
  constexpr int G1 = NI - G0;
  __shared__ alignas(16) uint16_t As[2][256 * 64];
  __shared__ alignas(16) uint16_t Bs[2][64 * NI * 64];

  int did = blockIdx.x;
  int wg = (did & 7) * (nwg >> 3) + (did >> 3);   // XCD swizzle (nwg % 8 == 0)
  int bx = wg % nbx, by = wg / nbx;
  int m0 = by * 256, n0 = bx * (64 * NI);

  int tid = threadIdx.x, lane = tid & 63, wid = tid >> 6;
  int wm = wid >> 2, wn = wid & 3;
  int l15 = lane & 15;
  int ko = (lane >> 4) * 8;
  int sw = (l15 & 7) * 8;              // read swizzle term (row&7 == l15&7)

  int srow = lane >> 3;                // staging: row-in-8
  int scol = ((lane & 7) ^ srow) * 8;  // pre-swizzled global col block

  f32x4 acc[8][NI] = {};

  auto stageA = [&](int buf, int t) {
    int k0 = t * 64;
#pragma unroll
    for (int i = 0; i < 4; ++i) {
      int r = wid * 32 + i * 8;
      gld16(&A[(size_t)(m0 + r + srow) * K + k0 + scol], &As[buf][r * 64]);
    }
  };
  auto stageB = [&](int buf, int t) {
    int k0 = t * 64;
#pragma unroll
    for (int i = 0; i < NI; ++i) {
      int r = wid * 8 * NI + i * 8;
      gld16(&B[(size_t)(n0 + r + srow) * K + k0 + scol], &Bs[buf][r * 64]);
    }
  };
  auto waitSteady = [&]() {
    if constexpr (NI == 3) asm volatile("s_waitcnt vmcnt(7)" ::: "memory");
    else                   asm volatile("s_waitcnt vmcnt(6)" ::: "memory");
  };

  // prologue: tiles 0 (buf0) and 1 (buf1); counted wait -> tile 0 landed
  stageA(0, 0); stageB(0, 0);
  stageA(1, 1); stageB(1, 1);
  waitSteady();
  __builtin_amdgcn_s_barrier();
  __builtin_amdgcn_sched_barrier(0);

  int nt = K >> 6;   // 16
  for (int t = 0; t < nt; ++t) {
    int buf = t & 1;
    const uint16_t* ap = &As[buf][0];
    const uint16_t* bp = &Bs[buf][0];
    bfx8 a[4][2], bg0[G0][2], bg1[G1][2], a2[4][2];

    // ---- P1: read A-low + B-G0; MFMA Q(lo,G0) ----
#pragma unroll
    for (int mi = 0; mi < 4; ++mi)
#pragma unroll
      for (int kk = 0; kk < 2; ++kk) {
        int r = wm * 128 + mi * 16 + l15;
        a[mi][kk] = *(const bfx8*)&ap[r * 64 + ((kk * 32 + ko) ^ sw)];
      }
#pragma unroll
    for (int ni = 0; ni < G0; ++ni)
#pragma unroll
      for (int kk = 0; kk < 2; ++kk) {
        int r = wn * (NI * 16) + ni * 16 + l15;
        bg0[ni][kk] = *(const bfx8*)&bp[r * 64 + ((kk * 32 + ko) ^ sw)];
      }
    __builtin_amdgcn_s_barrier();
    __builtin_amdgcn_s_setprio(1);
#pragma unroll
    for (int mi = 0; mi < 4; ++mi)
#pragma unroll
      for (int ni = 0; ni < G0; ++ni)
#pragma unroll
        for (int kk = 0; kk < 2; ++kk)
          acc[mi][ni] = __builtin_amdgcn_mfma_f32_16x16x32_bf16(a[mi][kk], bg0[ni][kk],
                                                                acc[mi][ni], 0, 0, 0);
    __builtin_amdgcn_s_setprio(0);
    __builtin_amdgcn_s_barrier();

    // ---- P2: read B-G1; MFMA Q(lo,G1) ----
#pragma unroll
    for (int ni = 0; ni < G1; ++ni)
#pragma unroll
      for (int kk = 0; kk < 2; ++kk) {
        int r = wn * (NI * 16) + (G0 + ni) * 16 + l15;
        bg1[ni][kk] = *(const bfx8*)&bp[r * 64 + ((kk * 32 + ko) ^ sw)];
      }
    __builtin_amdgcn_s_barrier();
    __builtin_amdgcn_s_setprio(1);
#pragma unroll
    for (int mi = 0; mi < 4; ++mi)
#pragma unroll
      for (int ni = 0; ni < G1; ++ni)
#pragma unroll
        for (int kk = 0; kk < 2; ++kk)
          acc[mi][G0 + ni] = __builtin_amdgcn_mfma_f32_16x16x32_bf16(a[mi][kk], bg1[ni][kk],
                                                                     acc[mi][G0 + ni], 0, 0, 0);
    __builtin_amdgcn_s_setprio(0);
    __builtin_amdgcn_s_barrier();

    // ---- P3: read A-high; stage B(t+2); MFMA Q(hi,G0) ----
#pragma unroll
    for (int mi = 0; mi < 4; ++mi)
#pragma unroll
      for (int kk = 0; kk < 2; ++kk) {
        int r = wm * 128 + (mi + 4) * 16 + l15;
        a2[mi][kk] = *(const bfx8*)&ap[r * 64 + ((kk * 32 + ko) ^ sw)];
      }
    if (t + 2 < nt) stageB(buf, t + 2);
    __builtin_amdgcn_s_barrier();
    __builtin_amdgcn_s_setprio(1);
#pragma unroll
    for (int mi = 0; mi < 4; ++mi)
#pragma unroll
      for (int ni = 0; ni < G0; ++ni)
#pragma unroll
        for (int kk = 0; kk < 2; ++kk)
          acc[mi + 4][ni] = __builtin_amdgcn_mfma_f32_16x16x32_bf16(a2[mi][kk], bg0[ni][kk],
                                                                    acc[mi + 4][ni], 0, 0, 0);
    __builtin_amdgcn_s_setprio(0);
    __builtin_amdgcn_s_barrier();

    // ---- P4: stage A(t+2); counted vmcnt; MFMA Q(hi,G1) ----
    if (t + 2 < nt) {
      stageA(buf, t + 2);
      waitSteady();                                        // t+2 in flight; t+1 landed
    } else if (t + 2 == nt) {
      asm volatile("s_waitcnt vmcnt(0)" ::: "memory");     // force tile nt-1
    }
    __builtin_amdgcn_sched_barrier(0);
    __builtin_amdgcn_s_barrier();
    __builtin_amdgcn_s_setprio(1);
#pragma unroll
    for (int mi = 0; mi < 4; ++mi)
#pragma unroll
      for (int ni = 0; ni < G1; ++ni)
#pragma unroll
        for (int kk = 0; kk < 2; ++kk)
          acc[mi + 4][G0 + ni] = __builtin_amdgcn_mfma_f32_16x16x32_bf16(a2[mi][kk], bg1[ni][kk],
                                                                         acc[mi + 4][G0 + ni], 0, 0, 0);
    __builtin_amdgcn_s_setprio(0);
    __builtin_amdgcn_s_barrier();
  }

  // epilogue: C/D layout col=lane&15, row=(lane>>4)*4+r
#pragma unroll
  for (int mi = 0; mi < 8; ++mi) {
    int row = m0 + wm * 128 + mi * 16 + ((lane >> 4) << 2);
#pragma unroll
    for (int ni = 0; ni < NI; ++ni) {
      int col = n0 + wn * (NI * 16) + ni * 16 + l15;
#pragma unroll
      for (int r = 0; r < 4; ++r) {
        float v = acc[mi][ni][r];
        if (OUTF32)
          ((float*)Cout)[(size_t)(row + r) * N + col] = v + bias[col];
        else
          ((uint16_t*)Cout)[(size_t)(row + r) * N + col] = f2b(v);
      }
    }
  }
}

// ---------------- flash attention (causal), pipelined 32x32 S^T / O^T ----------
// ROUND-5 CONFIG (best measured, 89us): 512 UNIFORM blocks: bh = d&63 (XCD
// locality), a = d>>6; block runs qb = 15-a then a -> exactly 34 kv-tiles.
// 4 waves x 32 q. Distance-2 prefetch; K triple-buffered LDS, V triple-buffered
// via 2-bank register staging. Raw s_barrier with COUNTED vmcnt(4).
// launch_bounds (256,2) (NOT (256,3): r6 spill; NOT 64q/wave: r10 spill).
__global__ __launch_bounds__(256, 2) void flash_attn(const uint16_t* __restrict__ qkv,
                                                     uint16_t* __restrict__ attnb) {
  const int T = 2048, D3 = 3072;
  const float CSC = 0.125f * 1.44269504f;  // scale * log2(e)
  __shared__ alignas(16) uint16_t Ks[3][64 * 64];
  __shared__ alignas(16) uint16_t Vt[3][64 * 64];   // V^T: [hd][kv]

  int d = blockIdx.x;
  int bh = d & 63;
  int a = d >> 6;              // 0..7
  int b = bh >> 4, h = bh & 15;

  int tid = threadIdx.x, lane = tid & 63, wid = tid >> 6;
  int l31 = lane & 31, hi = lane >> 5;
  int swz = (lane & 7) << 3;

  size_t base = (size_t)b * T * D3;
  int hoff = h * 64;
  const uint16_t* kbase = &qkv[base + 1024 + hoff];
  const uint16_t* vbase = &qkv[base + 2048 + hoff];

  int krow = wid * 16 + (lane >> 3);
  int kc = ((lane & 7) << 3) ^ ((krow & 7) << 3);
  int vr = (tid & 31) * 2;
  int vc = (tid >> 5) * 8;

  for (int p = 0; p < 2; ++p) {
    int qb = (p == 0) ? (15 - a) : a;   // long part first
    int q0 = qb << 7;
    int qw = q0 + wid * 32;
    int ntile = 2 * qb + 2;             // even

    float mC = -1e30f, l_r = 0.f;       // l_r: per-lane partial
    f32x16 acc0 = {}, acc1 = {};
    bfx8 pf[4];
    int smax_prev = -1, vb_prev = 0;

    // Q frags (B-operand): col=q=l31, k = hd = 16*h4 + 8*hi + j
    bfx8 qf[4];
    {
      const uint16_t* qp = &qkv[base + (size_t)(qw + l31) * D3 + hoff + 8 * hi];
#pragma unroll
      for (int h4 = 0; h4 < 4; ++h4) qf[h4] = *(const bfx8*)(qp + 16 * h4);
    }

    uint4 vA0, vA1, vB0, vB1;   // two V register banks (tile parity)

    auto loadV = [&](int kv0, uint4& r0, uint4& r1) {
      r0 = *(const uint4*)&vbase[(size_t)(kv0 + vr) * D3 + vc];
      r1 = *(const uint4*)&vbase[(size_t)(kv0 + vr + 1) * D3 + vc];
    };
    auto stageK = [&](int buf, int kv0) {
      gld16(&kbase[(size_t)(kv0 + krow) * D3 + kc], &Ks[buf][wid * 1024]);
      gld16(&kbase[(size_t)(kv0 + krow + 8) * D3 + kc], &Ks[buf][wid * 1024 + 512]);
    };
    auto writeV = [&](int vb, const uint4& r0, const uint4& r1) {
      union { uint4 v; uint16_t u[8]; } x, y;
      x.v = r0; y.v = r1;
#pragma unroll
      for (int jj = 0; jj < 8; ++jj) {
        int hd = vc + jj;
        uint32_t pk = (uint32_t)x.u[jj] | ((uint32_t)y.u[jj] << 16);
        *(uint32_t*)&Vt[vb][hd * 64 + (vr ^ ((hd & 7) << 3))] = pk;
      }
    };
    auto doPV = [&]() {
      const uint16_t* vp = &Vt[vb_prev][0];
      __builtin_amdgcn_s_setprio(1);
#pragma unroll
      for (int s = 0; s < 4; ++s) {
        if (s <= smax_prev) {
          bfx8 v0 = *(const bfx8*)&vp[l31 * 64 + ((16 * s + 8 * hi) ^ swz)];
          acc0 = __builtin_amdgcn_mfma_f32_32x32x16_bf16(v0, pf[s], acc0, 0, 0, 0);
          bfx8 v1 = *(const bfx8*)&vp[(32 + l31) * 64 + ((16 * s + 8 * hi) ^ swz)];
          acc1 = __builtin_amdgcn_mfma_f32_32x32x16_bf16(v1, pf[s], acc1, 0, 0, 0);
        }
      }
      __builtin_amdgcn_s_setprio(0);
    };

    // ---- prologue: stage tiles 0,1 fully; full drain once ----
    loadV(0, vA0, vA1);
    stageK(0, 0);
    writeV(0, vA0, vA1);
    loadV(64, vB0, vB1);
    stageK(1, 64);
    asm volatile("s_waitcnt vmcnt(0) lgkmcnt(0)" ::: "memory");
    __builtin_amdgcn_s_barrier();
    __builtin_amdgcn_sched_barrier(0);

    auto subiter = [&](int t, uint4& f0, uint4& f1, uint4& c0, uint4& c1) {
      int kv0 = t << 6;
      bool issue = (t + 2 < ntile);
      if (issue) {
        loadV((t + 2) << 6, f0, f1);
        stageK((t + 2) % 3, (t + 2) << 6);
      }
      bool active = (kv0 <= qw);
      int tmax = (qw > kv0) ? 2 : 1;
      f32x16 st0 = {}, st1 = {};
      if (active) {
        const uint16_t* kp = &Ks[t % 3][0];
        __builtin_amdgcn_s_setprio(1);
#pragma unroll
        for (int h4 = 0; h4 < 4; ++h4) {
          bfx8 kf0 = *(const bfx8*)&kp[l31 * 64 + ((16 * h4 + 8 * hi) ^ swz)];
          st0 = __builtin_amdgcn_mfma_f32_32x32x16_bf16(kf0, qf[h4], st0, 0, 0, 0);
          if (tmax == 2) {
            bfx8 kf1 = *(const bfx8*)&kp[(32 + l31) * 64 + ((16 * h4 + 8 * hi) ^ swz)];
            st1 = __builtin_amdgcn_mfma_f32_32x32x16_bf16(kf1, qf[h4], st1, 0, 0, 0);
          }
        }
        __builtin_amdgcn_s_setprio(0);
      }

      if (smax_prev >= 0) { doPV(); smax_prev = -1; }

      if (active) {
        int q = qw + l31;
        float mx0 = -1e30f, mx1 = -1e30f;
        if (kv0 == qw) {
#pragma unroll
          for (int r = 0; r < 16; ++r) {
            int kv = kv0 + (r & 3) + 8 * (r >> 2) + 4 * hi;
            float v = st0[r];
            if (kv > q) v = -1e30f;
            st0[r] = v;
            mx0 = fmaxf(mx0, v);
          }
        } else {
#pragma unroll
          for (int r = 0; r < 16; ++r) mx0 = fmaxf(mx0, st0[r]);
        }
        if (tmax == 2) {
          if (kv0 + 32 == qw) {
#pragma unroll
            for (int r = 0; r < 16; ++r) {
              int kv = kv0 + 32 + (r & 3) + 8 * (r >> 2) + 4 * hi;
              float v = st1[r];
              if (kv > q) v = -1e30f;
              st1[r] = v;
              mx1 = fmaxf(mx1, v);
            }
          } else {
#pragma unroll
            for (int r = 0; r < 16; ++r) mx1 = fmaxf(mx1, st1[r]);
          }
        }
        float mS = fmaxf(mx0, mx1) * CSC;
        if (!__all(mS - mC <= 8.0f)) {
          float mSp = fmaxf(mS, __shfl_xor(mS, 32));
          float mCn = fmaxf(mC, mSp);
          float fac = __builtin_amdgcn_exp2f(mC - mCn);
          mC = mCn;
          l_r *= fac;
          acc0 *= fac;
          acc1 *= fac;
        }
        float l0 = 0.f, l1 = 0.f, l2 = 0.f, l3 = 0.f;
#pragma unroll
        for (int r = 0; r < 16; r += 4) {
          float e0 = __builtin_amdgcn_exp2f(fmaf(st0[r], CSC, -mC));
          float e1 = __builtin_amdgcn_exp2f(fmaf(st0[r + 1], CSC, -mC));
          float e2 = __builtin_amdgcn_exp2f(fmaf(st0[r + 2], CSC, -mC));
          float e3 = __builtin_amdgcn_exp2f(fmaf(st0[r + 3], CSC, -mC));
          st0[r] = e0; st0[r + 1] = e1; st0[r + 2] = e2; st0[r + 3] = e3;
          l0 += e0; l1 += e1; l2 += e2; l3 += e3;
        }
        if (tmax == 2) {
#pragma unroll
          for (int r = 0; r < 16; r += 4) {
            float e0 = __builtin_amdgcn_exp2f(fmaf(st1[r], CSC, -mC));
            float e1 = __builtin_amdgcn_exp2f(fmaf(st1[r + 1], CSC, -mC));
            float e2 = __builtin_amdgcn_exp2f(fmaf(st1[r + 2], CSC, -mC));
            float e3 = __builtin_amdgcn_exp2f(fmaf(st1[r + 3], CSC, -mC));
            st1[r] = e0; st1[r + 1] = e1; st1[r + 2] = e2; st1[r + 3] = e3;
            l0 += e0; l1 += e1; l2 += e2; l3 += e3;
          }
        }
        l_r += (l0 + l1) + (l2 + l3);

        int smax = (qw + 31 - kv0) >> 4;
        if (smax > 3) smax = 3;
#pragma unroll
        for (int s = 0; s < 4; ++s) {
          if (s <= smax) {
            int pb = 8 * (s & 1);
            uint32_t W0, W1, W2, W3;
            if (s < 2) {
              W0 = cvt_pk(st0[pb + 0], st0[pb + 1]);
              W1 = cvt_pk(st0[pb + 2], st0[pb + 3]);
              W2 = cvt_pk(st0[pb + 4], st0[pb + 5]);
              W3 = cvt_pk(st0[pb + 6], st0[pb + 7]);
            } else {
              W0 = cvt_pk(st1[pb + 0], st1[pb + 1]);
              W1 = cvt_pk(st1[pb + 2], st1[pb + 3]);
              W2 = cvt_pk(st1[pb + 4], st1[pb + 5]);
              W3 = cvt_pk(st1[pb + 6], st1[pb + 7]);
            }
            auto rA = __builtin_amdgcn_permlane32_swap(W0, W2, false, false);
            auto rB = __builtin_amdgcn_permlane32_swap(W1, W3, false, false);
            union { uint32_t u[4]; bfx8 v; } pk;
            pk.u[0] = rA[0]; pk.u[1] = rB[0]; pk.u[2] = rA[1]; pk.u[3] = rB[1];
            pf[s] = pk.v;
          }
        }
        smax_prev = smax;
        vb_prev = t % 3;
      }

      if (t + 1 < ntile) writeV((t + 1) % 3, c0, c1);

      if (issue)
        asm volatile("s_waitcnt vmcnt(4) lgkmcnt(0)" ::: "memory");
      else
        asm volatile("s_waitcnt vmcnt(0) lgkmcnt(0)" ::: "memory");
      __builtin_amdgcn_s_barrier();
      __builtin_amdgcn_sched_barrier(0);
    };

    for (int t = 0; t < ntile; t += 2) {
      subiter(t, vA0, vA1, vB0, vB1);
      subiter(t + 1, vB0, vB1, vA0, vA1);
    }
    if (smax_prev >= 0) doPV();

    // ---- epilogue ----
    float l_tot = l_r + __shfl_xor(l_r, 32);
    __syncthreads();
    uint16_t* ow = ((uint16_t*)Ks) + wid * 2048;
    float rl = 1.0f / l_tot;
#pragma unroll
    for (int f = 0; f < 2; ++f) {
#pragma unroll
      for (int r = 0; r < 16; r += 2) {
        int hd = 32 * f + (r & 3) + 8 * (r >> 2) + 4 * hi;
        float v0 = (f ? acc1[r] : acc0[r]) * rl;
        float v1 = (f ? acc1[r + 1] : acc0[r + 1]) * rl;
        *(uint32_t*)&ow[l31 * 64 + (hd ^ ((l31 & 7) << 3))] = cvt_pk(v0, v1);
      }
    }
    int row = lane >> 1, cb = (lane & 1) * 32;
    int q = q0 + wid * 32 + row;
    int rs = (row & 7) << 3;
    uint16_t* dst = &attnb[(size_t)(b * T + q) * 1024 + hoff + cb];
#pragma unroll
    for (int cc = 0; cc < 4; ++cc)
      *(uint4*)&dst[cc * 8] = *(const uint4*)&ow[row * 64 + ((cb + cc * 8) ^ rs)];
    __syncthreads();
  }
}

// ---------------- host ----------------
extern "C" void kernel_launch(void* const* d_in, const int* in_sizes, int n_in,
                              void* d_out, int out_size, void* d_ws, size_t ws_size,
                              hipStream_t stream) {
  const float* x = (const float*)d_in[0];
  const float* qkv_w = (const float*)d_in[1];
  const float* out_w = (const float*)d_in[2];
  const float* out_b = (const float*)d_in[3];
  float* out = (float*)d_out;

  char* ws = (char*)d_ws;
  uint16_t* xb    = (uint16_t*)(ws);
  uint16_t* qkvb  = (uint16_t*)(ws + 16777216);
  uint16_t* attnb = (uint16_t*)(ws + 67108864);
  uint16_t* wqkvb = (uint16_t*)(ws + 83886080);
  uint16_t* wob   = (uint16_t*)(ws + 90177536);

  cvt_all<<<6144, 256, 0, stream>>>(x, qkv_w, out_w, xb, wqkvb, wob);

  // qkv = x @ qkv_w^T : M=8192 N=3072 K=1024, 256x192 tiles -> grid 32*16 = 512
  gemm8p<3, 0><<<512, 512, 0, stream>>>(xb, wqkvb, (void*)qkvb, nullptr,
                                        8192, 3072, 1024, 16, 512);
  flash_attn<<<512, 256, 0, stream>>>(qkvb, attnb);
  // out = attn @ out_w^T + b : M=8192 N=1024 K=1024, 256x128 tiles -> grid 32*8 = 256
  gemm8p<2, 1><<<256, 512, 0, stream>>>(attnb, wob, (void*)out, out_b,
                                        8192, 1024, 1024, 8, 256);
}